// Round 9
// baseline (418.464 us; speedup 1.0000x reference)
//
#include <hip/hip_runtime.h>
#include <hip/hip_bf16.h>

#define BATCH 65536
#define DK 512
#define DV 512
#define DH 64
#define BM 64
#define NT (DV / 16)   // 32 column-iterations

typedef __attribute__((ext_vector_type(8))) short bf16x8;
typedef __attribute__((ext_vector_type(4))) float f32x4;

// LINEAR bf16 weight images (read global->reg, no LDS, no swizzle):
//   [0]      W1  (64 x 512)
//   [32768]  W2  (512 x 64)
//   [65536]  Wp  (512 x 512)
__device__ __align__(16) short g_wb[327680];

__device__ __forceinline__ short f2bf(float f) {
    union { __hip_bfloat16 h; short s; } u;
    u.h = __float2bfloat16(f);
    return u.s;
}

__device__ __forceinline__ bf16x8 pack8(float4 a, float4 b) {
    bf16x8 r;
    r[0] = f2bf(a.x); r[1] = f2bf(a.y); r[2] = f2bf(a.z); r[3] = f2bf(a.w);
    r[4] = f2bf(b.x); r[5] = f2bf(b.y); r[6] = f2bf(b.z); r[7] = f2bf(b.w);
    return r;
}

__global__ __launch_bounds__(256) void conv_weights(
    const float* __restrict__ W1, const float* __restrict__ W2,
    const float* __restrict__ Wp)
{
    int t = blockIdx.x * 256 + threadIdx.x;   // 40960 threads x 8 elems
    long e = (long)t * 8;
    const float* src; long off;
    if (e < 32768)      { src = W1; off = e; }
    else if (e < 65536) { src = W2; off = e - 32768; }
    else                { src = Wp; off = e - 65536; }
    float4 a = *reinterpret_cast<const float4*>(src + off);
    float4 b = *reinterpret_cast<const float4*>(src + off + 4);
    *reinterpret_cast<bf16x8*>(g_wb + e) = pack8(a, b);
}

__global__ __launch_bounds__(256, 3) void fused_free_energy(
    const float* __restrict__ key, const float* __restrict__ value,
    const float* __restrict__ b1, const float* __restrict__ b2,
    const float* __restrict__ pb,
    float* __restrict__ outF, float* __restrict__ outPred,
    float* __restrict__ outPrec, float* __restrict__ outErr)
{
    __shared__ __align__(16) short hpark[4096];   // 8 KB: h redistribution only
    char* hpb = reinterpret_cast<char*>(hpark);

    const short* W1b = g_wb;
    const short* W2b = g_wb + 32768;
    const short* Wpb = g_wb + 65536;

    const int tid  = threadIdx.x;
    const int wave = tid >> 6;
    const int lane = tid & 63;
    const int lh   = lane & 15;
    const int lg   = lane >> 4;
    const long row0 = (long)blockIdx.x * BM;
    const f32x4 zf = {0.f, 0.f, 0.f, 0.f};

    // ---- key fragments: straight global -> reg (coalesced per 128B line) ----
    bf16x8 kreg[16];
    {
        const float* krow = key + (row0 + wave * 16 + lh) * DK + lg * 8;
        #pragma unroll
        for (int kk = 0; kk < 16; ++kk) {
            float4 a = *reinterpret_cast<const float4*>(krow + kk * 32);
            float4 b = *reinterpret_cast<const float4*>(krow + kk * 32 + 4);
            kreg[kk] = pack8(a, b);
        }
    }

    // ---- GEMM1: h = gelu(key @ W1^T + b1); W1 frags direct from L2 ----
    short hs_all[16];
    #pragma unroll
    for (int jt = 0; jt < 4; ++jt) {
        const short* wt = W1b + (jt * 16 + lh) * DK + lg * 8;
        f32x4 aE = zf, aO = zf;   // two independent chains (even/odd kk)
        #pragma unroll
        for (int kk = 0; kk < 16; kk += 2) {
            bf16x8 f0 = *reinterpret_cast<const bf16x8*>(wt + kk * 32);
            bf16x8 f1 = *reinterpret_cast<const bf16x8*>(wt + kk * 32 + 32);
            aE = __builtin_amdgcn_mfma_f32_16x16x32_bf16(f0, kreg[kk],     aE, 0, 0, 0);
            aO = __builtin_amdgcn_mfma_f32_16x16x32_bf16(f1, kreg[kk + 1], aO, 0, 0, 0);
        }
        float4 b1v = *reinterpret_cast<const float4*>(b1 + jt * 16 + lg * 4);
        float b1a[4] = {b1v.x, b1v.y, b1v.z, b1v.w};
        #pragma unroll
        for (int r = 0; r < 4; ++r) {
            float z = aE[r] + aO[r] + b1a[r];
            float g = 0.5f * z * (1.0f + erff(z * 0.70710678f));  // exact GELU
            hs_all[jt * 4 + r] = f2bf(g);
        }
    }
    // park h (wave-private 2KB slots) in B-fragment layout, then reload
    #pragma unroll
    for (int jt = 0; jt < 4; ++jt) {
        int hb = wave * 2048 + ((lh * 128 + jt * 32 + lg * 8) ^ ((lh & 7) << 4));
        short4 hv = {hs_all[jt * 4 + 0], hs_all[jt * 4 + 1],
                     hs_all[jt * 4 + 2], hs_all[jt * 4 + 3]};
        *reinterpret_cast<short4*>(hpb + hb) = hv;
    }
    __syncthreads();
    bf16x8 hreg[2];
    #pragma unroll
    for (int kh = 0; kh < 2; ++kh) {
        int byte = (lh * 128 + kh * 64 + lg * 16) ^ ((lh & 7) << 4);
        hreg[kh] = *reinterpret_cast<const bf16x8*>(hpb + wave * 2048 + byte);
    }

    // ---- main loop: 32 x 16 output cols; weights from L2, NO barriers ----
    {
        float facc = 0.f;
        const long grow = row0 + wave * 16 + lh;
        const float* vrow = value + grow * DV;
        float* prow = outPred + grow * DV;
        float* crow = outPrec + grow * DV;
        float* erow = outErr  + grow * DV;

        float4 vcur = *reinterpret_cast<const float4*>(vrow + lg * 4);

        for (int it = 0; it < NT; ++it) {
            int nb = it * 16 + lg * 4;

            // prefetch next iteration's value (hide HBM latency)
            float4 vnx;
            if (it + 1 < NT)
                vnx = *reinterpret_cast<const float4*>(vrow + nb + 16);

            // GEMM3: Wp frags direct from L2; two independent MFMA chains
            const short* wt = Wpb + ((long)it * 16 + lh) * DK + lg * 8;
            f32x4 aE = zf, aO = zf;
            #pragma unroll
            for (int kk = 0; kk < 16; kk += 2) {
                bf16x8 f0 = *reinterpret_cast<const bf16x8*>(wt + kk * 32);
                bf16x8 f1 = *reinterpret_cast<const bf16x8*>(wt + kk * 32 + 32);
                aE = __builtin_amdgcn_mfma_f32_16x16x32_bf16(f0, kreg[kk],     aE, 0, 0, 0);
                aO = __builtin_amdgcn_mfma_f32_16x16x32_bf16(f1, kreg[kk + 1], aO, 0, 0, 0);
            }
            // GEMM2: W2 frags direct from L2
            const short* w2t = W2b + ((long)it * 16 + lh) * DH + lg * 8;
            f32x4 acc2 = zf;
            #pragma unroll
            for (int kh = 0; kh < 2; ++kh) {
                bf16x8 f = *reinterpret_cast<const bf16x8*>(w2t + kh * 32);
                acc2 = __builtin_amdgcn_mfma_f32_16x16x32_bf16(f, hreg[kh], acc2, 0, 0, 0);
            }

            // epilogue: lane holds 4 consecutive cols (n = nb + r) of row grow
            float4 b2v = *reinterpret_cast<const float4*>(b2 + nb);
            float4 pbv = *reinterpret_cast<const float4*>(pb + nb);
            float b2a[4] = {b2v.x, b2v.y, b2v.z, b2v.w};
            float pba[4] = {pbv.x, pbv.y, pbv.z, pbv.w};
            float va[4]  = {vcur.x, vcur.y, vcur.z, vcur.w};
            float prv[4], pcv[4], erv[4];
            #pragma unroll
            for (int r = 0; r < 4; ++r) {
                float pred = aE[r] + aO[r] + pba[r];          // placeholder names fixed below
                // NOTE: aE+aO is z3 (prec head); acc2 is pred
                float z    = pred;                            // z = z3 + pb
                pred = acc2[r] + b2a[r];
                float prec = fmaxf(z, 0.f) + __logf(1.0f + __expf(-fabsf(z))) + 0.01f;
                float err  = fminf(fmaxf(va[r] - pred, -3.f), 3.f);
                prv[r] = pred; pcv[r] = prec; erv[r] = err;
                facc += prec * err * err - __logf(prec);
            }
            float4 pr4 = {prv[0], prv[1], prv[2], prv[3]};
            float4 pc4 = {pcv[0], pcv[1], pcv[2], pcv[3]};
            float4 er4 = {erv[0], erv[1], erv[2], erv[3]};
            *reinterpret_cast<float4*>(prow + nb) = pr4;
            *reinterpret_cast<float4*>(crow + nb) = pc4;
            *reinterpret_cast<float4*>(erow + nb) = er4;

            vcur = vnx;
        }

        // F: sum the 4 lg-lanes holding the same row
        facc += __shfl_xor(facc, 16, 64);
        facc += __shfl_xor(facc, 32, 64);
        if (lane < 16) outF[grow] = facc * (1.0f / 512.0f);
    }
}

extern "C" void kernel_launch(void* const* d_in, const int* in_sizes, int n_in,
                              void* d_out, int out_size, void* d_ws, size_t ws_size,
                              hipStream_t stream) {
    const float* key   = (const float*)d_in[0];
    const float* value = (const float*)d_in[1];
    const float* W1    = (const float*)d_in[2];
    const float* b1    = (const float*)d_in[3];
    const float* W2    = (const float*)d_in[4];
    const float* b2    = (const float*)d_in[5];
    const float* Wp    = (const float*)d_in[6];
    const float* pb    = (const float*)d_in[7];

    float* outF    = (float*)d_out;
    float* outPred = outF + BATCH;
    float* outPrec = outPred + (long)BATCH * DV;
    float* outErr  = outPrec + (long)BATCH * DV;

    conv_weights<<<160, 256, 0, stream>>>(W1, W2, Wp);
    fused_free_energy<<<BATCH / BM, 256, 0, stream>>>(key, value, b1, b2, pb,
                                                      outF, outPred, outPrec, outErr);
}

// Round 10
// 395.752 us; speedup vs baseline: 1.0574x; 1.0574x over previous
//
#include <hip/hip_runtime.h>
#include <hip/hip_bf16.h>

#define BATCH 65536
#define DK 512
#define DV 512
#define DH 64
#define BM 64
#define NT (DV / 16)   // 32 column-iterations

typedef __attribute__((ext_vector_type(8))) short bf16x8;
typedef __attribute__((ext_vector_type(4))) float f32x4;

// FRAGMENT-ORDERED bf16 weight images: for each (tile, k-step), the 64 lanes'
// 16B MFMA A-fragments stored contiguously -> one fully-coalesced 1KB load/wave.
//   shorts [0, 32768):       W1F  (4 tiles x 16 kk x 64 lanes x 8)
//   shorts [32768, 65536):   W2F  (32 tiles x 2 kh x 64 lanes x 8)
//   shorts [65536, 327680):  WpF  (32 tiles x 16 kk x 64 lanes x 8)
__device__ __align__(16) short g_wb[327680];

__device__ __forceinline__ short f2bf(float f) {
    union { __hip_bfloat16 h; short s; } u;
    u.h = __float2bfloat16(f);
    return u.s;
}

__device__ __forceinline__ bf16x8 pack8(float4 a, float4 b) {
    bf16x8 r;
    r[0] = f2bf(a.x); r[1] = f2bf(a.y); r[2] = f2bf(a.z); r[3] = f2bf(a.w);
    r[4] = f2bf(b.x); r[5] = f2bf(b.y); r[6] = f2bf(b.z); r[7] = f2bf(b.w);
    return r;
}

// one thread = one 8-elem fragment; 40960 threads total
__global__ __launch_bounds__(256) void conv_weights(
    const float* __restrict__ W1, const float* __restrict__ W2,
    const float* __restrict__ Wp)
{
    int f = blockIdx.x * 256 + threadIdx.x;
    int lane = f & 63;
    const float* src; int stride, row, col;
    if (f < 4096) {                    // W1F: A-frag of W1 rows (hidden units)
        int t = f >> 10, kk = (f >> 6) & 15;
        src = W1; stride = DK;
        row = t * 16 + (lane & 15); col = kk * 32 + (lane >> 4) * 8;
    } else if (f < 8192) {             // W2F: A-frag of W2 rows (output cols)
        int g = f - 4096; int t = g >> 7, kh = (g >> 6) & 1;
        src = W2; stride = DH;
        row = t * 16 + (lane & 15); col = kh * 32 + (lane >> 4) * 8;
    } else {                           // WpF: A-frag of Wp rows (output cols)
        int g = f - 8192; int t = g >> 10, kk = (g >> 6) & 15;
        src = Wp; stride = DK;
        row = t * 16 + (lane & 15); col = kk * 32 + (lane >> 4) * 8;
    }
    const float* p = src + (long)row * stride + col;
    float4 a = *reinterpret_cast<const float4*>(p);
    float4 b = *reinterpret_cast<const float4*>(p + 4);
    *reinterpret_cast<bf16x8*>(g_wb + (long)f * 8) = pack8(a, b);
}

__global__ __launch_bounds__(256, 4) void fused_free_energy(
    const float* __restrict__ key, const float* __restrict__ value,
    const float* __restrict__ b1, const float* __restrict__ b2,
    const float* __restrict__ pb,
    float* __restrict__ outF, float* __restrict__ outPred,
    float* __restrict__ outPrec, float* __restrict__ outErr)
{
    __shared__ __align__(16) short hpark[4096];   // 8 KB: h redistribution only
    char* hpb = reinterpret_cast<char*>(hpark);

    const bf16x8* W1F = reinterpret_cast<const bf16x8*>(g_wb);
    const bf16x8* W2F = reinterpret_cast<const bf16x8*>(g_wb + 32768);
    const bf16x8* WpF = reinterpret_cast<const bf16x8*>(g_wb + 65536);

    const int tid  = threadIdx.x;
    const int wave = tid >> 6;
    const int lane = tid & 63;
    const int lh   = lane & 15;
    const int lg   = lane >> 4;
    const long row0 = (long)blockIdx.x * BM;
    const f32x4 zf = {0.f, 0.f, 0.f, 0.f};

    // ---- key fragments: straight global -> reg ----
    bf16x8 kreg[16];
    {
        const float* krow = key + (row0 + wave * 16 + lh) * DK + lg * 8;
        #pragma unroll
        for (int kk = 0; kk < 16; ++kk) {
            float4 a = *reinterpret_cast<const float4*>(krow + kk * 32);
            float4 b = *reinterpret_cast<const float4*>(krow + kk * 32 + 4);
            kreg[kk] = pack8(a, b);
        }
    }

    // ---- GEMM1: h = gelu(key @ W1^T + b1); W1 frags coalesced from L2 ----
    short hs_all[16];
    #pragma unroll
    for (int jt = 0; jt < 4; ++jt) {
        f32x4 aE = zf, aO = zf;   // two independent chains
        #pragma unroll
        for (int kk = 0; kk < 16; kk += 2) {
            bf16x8 f0 = W1F[(jt * 16 + kk) * 64 + lane];
            bf16x8 f1 = W1F[(jt * 16 + kk + 1) * 64 + lane];
            aE = __builtin_amdgcn_mfma_f32_16x16x32_bf16(f0, kreg[kk],     aE, 0, 0, 0);
            aO = __builtin_amdgcn_mfma_f32_16x16x32_bf16(f1, kreg[kk + 1], aO, 0, 0, 0);
        }
        float4 b1v = *reinterpret_cast<const float4*>(b1 + jt * 16 + lg * 4);
        float b1a[4] = {b1v.x, b1v.y, b1v.z, b1v.w};
        #pragma unroll
        for (int r = 0; r < 4; ++r) {
            float z = aE[r] + aO[r] + b1a[r];
            float g = 0.5f * z * (1.0f + erff(z * 0.70710678f));  // exact GELU
            hs_all[jt * 4 + r] = f2bf(g);
        }
    }
    // park h (wave-private 2KB slots) in B-fragment layout, then reload
    #pragma unroll
    for (int jt = 0; jt < 4; ++jt) {
        int hb = wave * 2048 + ((lh * 128 + jt * 32 + lg * 8) ^ ((lh & 7) << 4));
        short4 hv = {hs_all[jt * 4 + 0], hs_all[jt * 4 + 1],
                     hs_all[jt * 4 + 2], hs_all[jt * 4 + 3]};
        *reinterpret_cast<short4*>(hpb + hb) = hv;
    }
    __syncthreads();
    bf16x8 hreg[2];
    #pragma unroll
    for (int kh = 0; kh < 2; ++kh) {
        int byte = (lh * 128 + kh * 64 + lg * 16) ^ ((lh & 7) << 4);
        hreg[kh] = *reinterpret_cast<const bf16x8*>(hpb + wave * 2048 + byte);
    }

    // ---- main loop: 32 x 16 output cols; coalesced L2 frags, NO barriers ----
    {
        float facc = 0.f;
        const long grow = row0 + wave * 16 + lh;
        const float* vrow = value + grow * DV;
        float* prow = outPred + grow * DV;
        float* crow = outPrec + grow * DV;
        float* erow = outErr  + grow * DV;

        float4 vcur = *reinterpret_cast<const float4*>(vrow + lg * 4);

        for (int it = 0; it < NT; ++it) {
            int nb = it * 16 + lg * 4;

            // prefetch next iteration's value (hide HBM latency)
            float4 vnx;
            if (it + 1 < NT)
                vnx = *reinterpret_cast<const float4*>(vrow + nb + 16);

            // GEMM3: coalesced Wp frags; two independent MFMA chains
            f32x4 aE = zf, aO = zf;
            #pragma unroll
            for (int kk = 0; kk < 16; kk += 2) {
                bf16x8 f0 = WpF[(it * 16 + kk) * 64 + lane];
                bf16x8 f1 = WpF[(it * 16 + kk + 1) * 64 + lane];
                aE = __builtin_amdgcn_mfma_f32_16x16x32_bf16(f0, kreg[kk],     aE, 0, 0, 0);
                aO = __builtin_amdgcn_mfma_f32_16x16x32_bf16(f1, kreg[kk + 1], aO, 0, 0, 0);
            }
            // GEMM2: coalesced W2 frags
            f32x4 acc2 = zf;
            #pragma unroll
            for (int kh = 0; kh < 2; ++kh) {
                bf16x8 f = W2F[(it * 2 + kh) * 64 + lane];
                acc2 = __builtin_amdgcn_mfma_f32_16x16x32_bf16(f, hreg[kh], acc2, 0, 0, 0);
            }

            // epilogue: lane holds 4 consecutive cols (n = nb + r) of row grow
            float4 b2v = *reinterpret_cast<const float4*>(b2 + nb);
            float4 pbv = *reinterpret_cast<const float4*>(pb + nb);
            float b2a[4] = {b2v.x, b2v.y, b2v.z, b2v.w};
            float pba[4] = {pbv.x, pbv.y, pbv.z, pbv.w};
            float va[4]  = {vcur.x, vcur.y, vcur.z, vcur.w};
            float prv[4], pcv[4], erv[4];
            #pragma unroll
            for (int r = 0; r < 4; ++r) {
                float z    = aE[r] + aO[r] + pba[r];      // prec-head logit
                float pred = acc2[r] + b2a[r];
                float prec = fmaxf(z, 0.f) + __logf(1.0f + __expf(-fabsf(z))) + 0.01f;
                float err  = fminf(fmaxf(va[r] - pred, -3.f), 3.f);
                prv[r] = pred; pcv[r] = prec; erv[r] = err;
                facc += prec * err * err - __logf(prec);
            }
            float4 pr4 = {prv[0], prv[1], prv[2], prv[3]};
            float4 pc4 = {pcv[0], pcv[1], pcv[2], pcv[3]};
            float4 er4 = {erv[0], erv[1], erv[2], erv[3]};
            *reinterpret_cast<float4*>(prow + nb) = pr4;
            *reinterpret_cast<float4*>(crow + nb) = pc4;
            *reinterpret_cast<float4*>(erow + nb) = er4;

            vcur = vnx;
        }

        // F: sum the 4 lg-lanes holding the same row
        facc += __shfl_xor(facc, 16, 64);
        facc += __shfl_xor(facc, 32, 64);
        if (lane < 16) outF[grow] = facc * (1.0f / 512.0f);
    }
}

extern "C" void kernel_launch(void* const* d_in, const int* in_sizes, int n_in,
                              void* d_out, int out_size, void* d_ws, size_t ws_size,
                              hipStream_t stream) {
    const float* key   = (const float*)d_in[0];
    const float* value = (const float*)d_in[1];
    const float* W1    = (const float*)d_in[2];
    const float* b1    = (const float*)d_in[3];
    const float* W2    = (const float*)d_in[4];
    const float* b2    = (const float*)d_in[5];
    const float* Wp    = (const float*)d_in[6];
    const float* pb    = (const float*)d_in[7];

    float* outF    = (float*)d_out;
    float* outPred = outF + BATCH;
    float* outPrec = outPred + (long)BATCH * DV;
    float* outErr  = outPrec + (long)BATCH * DV;

    conv_weights<<<160, 256, 0, stream>>>(W1, W2, Wp);
    fused_free_energy<<<BATCH / BM, 256, 0, stream>>>(key, value, b1, b2, pb,
                                                      outF, outPred, outPrec, outErr);
}

// Round 11
// 300.025 us; speedup vs baseline: 1.3948x; 1.3191x over previous
//
#include <hip/hip_runtime.h>
#include <hip/hip_bf16.h>

#define BATCH 65536
#define DK 512
#define DV 512
#define DH 64
#define BMR 16          // rows per block
#define NIT 8           // col-tile iterations per wave (4 waves x 8 x 16 = 512 cols)

typedef __attribute__((ext_vector_type(8))) short bf16x8;
typedef __attribute__((ext_vector_type(4))) float f32x4;

// FRAGMENT-ORDERED bf16 weight images: for each (tile, k-step), the 64 lanes'
// 16B MFMA A-fragments stored contiguously -> one fully-coalesced 1KB load/wave.
//   shorts [0, 32768):       W1F  (4 tiles x 16 kk x 64 lanes x 8)
//   shorts [32768, 65536):   W2F  (32 tiles x 2 kh x 64 lanes x 8)
//   shorts [65536, 327680):  WpF  (32 tiles x 16 kk x 64 lanes x 8)
__device__ __align__(16) short g_wb[327680];

__device__ __forceinline__ short f2bf(float f) {
    union { __hip_bfloat16 h; short s; } u;
    u.h = __float2bfloat16(f);
    return u.s;
}

__device__ __forceinline__ bf16x8 pack8(float4 a, float4 b) {
    bf16x8 r;
    r[0] = f2bf(a.x); r[1] = f2bf(a.y); r[2] = f2bf(a.z); r[3] = f2bf(a.w);
    r[4] = f2bf(b.x); r[5] = f2bf(b.y); r[6] = f2bf(b.z); r[7] = f2bf(b.w);
    return r;
}

// one thread = one 8-elem fragment; 40960 threads total
__global__ __launch_bounds__(256) void conv_weights(
    const float* __restrict__ W1, const float* __restrict__ W2,
    const float* __restrict__ Wp)
{
    int f = blockIdx.x * 256 + threadIdx.x;
    int lane = f & 63;
    const float* src; int stride, row, col;
    if (f < 4096) {                    // W1F
        int t = f >> 10, kk = (f >> 6) & 15;
        src = W1; stride = DK;
        row = t * 16 + (lane & 15); col = kk * 32 + (lane >> 4) * 8;
    } else if (f < 8192) {             // W2F
        int g = f - 4096; int t = g >> 7, kh = (g >> 6) & 1;
        src = W2; stride = DH;
        row = t * 16 + (lane & 15); col = kh * 32 + (lane >> 4) * 8;
    } else {                           // WpF
        int g = f - 8192; int t = g >> 10, kk = (g >> 6) & 15;
        src = Wp; stride = DK;
        row = t * 16 + (lane & 15); col = kk * 32 + (lane >> 4) * 8;
    }
    const float* p = src + (long)row * stride + col;
    float4 a = *reinterpret_cast<const float4*>(p);
    float4 b = *reinterpret_cast<const float4*>(p + 4);
    *reinterpret_cast<bf16x8*>(g_wb + (long)f * 8) = pack8(a, b);
}

__global__ __launch_bounds__(256, 3) void fused_free_energy(
    const float* __restrict__ key, const float* __restrict__ value,
    const float* __restrict__ b1, const float* __restrict__ b2,
    const float* __restrict__ pb,
    float* __restrict__ outF, float* __restrict__ outPred,
    float* __restrict__ outPrec, float* __restrict__ outErr)
{
    // 32 KB: h-park (first 8KB, transient) then 16x512 f32 transpose buffer
    __shared__ __align__(16) char xbuf[32768];

    const bf16x8* W1F = reinterpret_cast<const bf16x8*>(g_wb);
    const bf16x8* W2F = reinterpret_cast<const bf16x8*>(g_wb + 32768);
    const bf16x8* WpF = reinterpret_cast<const bf16x8*>(g_wb + 65536);

    const int tid  = threadIdx.x;
    const int wave = tid >> 6;
    const int lane = tid & 63;
    const int lh   = lane & 15;
    const int lg   = lane >> 4;
    const long row0 = (long)blockIdx.x * BMR;
    const f32x4 zf = {0.f, 0.f, 0.f, 0.f};

    // ---- key fragments: the block's 16 rows (same for all 4 waves) ----
    bf16x8 kreg[16];
    {
        const float* krow = key + (row0 + lh) * DK + lg * 8;
        #pragma unroll
        for (int kk = 0; kk < 16; ++kk) {
            float4 a = *reinterpret_cast<const float4*>(krow + kk * 32);
            float4 b = *reinterpret_cast<const float4*>(krow + kk * 32 + 4);
            kreg[kk] = pack8(a, b);
        }
    }

    // ---- GEMM1: h = gelu(key @ W1^T + b1); computed per-wave (redundant, tiny) ----
    short hs_all[16];
    #pragma unroll
    for (int jt = 0; jt < 4; ++jt) {
        f32x4 aE = zf, aO = zf;
        #pragma unroll
        for (int kk = 0; kk < 16; kk += 2) {
            bf16x8 f0 = W1F[(jt * 16 + kk) * 64 + lane];
            bf16x8 f1 = W1F[(jt * 16 + kk + 1) * 64 + lane];
            aE = __builtin_amdgcn_mfma_f32_16x16x32_bf16(f0, kreg[kk],     aE, 0, 0, 0);
            aO = __builtin_amdgcn_mfma_f32_16x16x32_bf16(f1, kreg[kk + 1], aO, 0, 0, 0);
        }
        float4 b1v = *reinterpret_cast<const float4*>(b1 + jt * 16 + lg * 4);
        float b1a[4] = {b1v.x, b1v.y, b1v.z, b1v.w};
        #pragma unroll
        for (int r = 0; r < 4; ++r) {
            float z = aE[r] + aO[r] + b1a[r];
            float g = 0.5f * z * (1.0f + erff(z * 0.70710678f));  // exact GELU
            hs_all[jt * 4 + r] = f2bf(g);
        }
    }
    // park h (wave-private 2KB slot) in B-fragment layout, reload as hreg
    #pragma unroll
    for (int jt = 0; jt < 4; ++jt) {
        int hb = wave * 2048 + ((lh * 128 + jt * 32 + lg * 8) ^ ((lh & 7) << 4));
        short4 hv = {hs_all[jt * 4 + 0], hs_all[jt * 4 + 1],
                     hs_all[jt * 4 + 2], hs_all[jt * 4 + 3]};
        *reinterpret_cast<short4*>(xbuf + hb) = hv;
    }
    __syncthreads();
    bf16x8 hreg[2];
    #pragma unroll
    for (int kh = 0; kh < 2; ++kh) {
        int byte = (lh * 128 + kh * 64 + lg * 16) ^ ((lh & 7) << 4);
        hreg[kh] = *reinterpret_cast<const bf16x8*>(xbuf + wave * 2048 + byte);
    }
    __syncthreads();   // h-park dead; xbuf free for writeback staging

    // ---- main loop: wave covers cols [wave*128, wave*128+128), 8 tile-iters ----
    // results held in registers; NO stores, NO value reads, NO barriers here
    f32x4 predz[NIT], z3v[NIT];
    #pragma unroll
    for (int it = 0; it < NIT; ++it) {
        const int tile = wave * NIT + it;            // global col-tile 0..31
        f32x4 aE = zf, aO = zf;
        #pragma unroll
        for (int kk = 0; kk < 16; kk += 2) {
            bf16x8 f0 = WpF[(tile * 16 + kk) * 64 + lane];
            bf16x8 f1 = WpF[(tile * 16 + kk + 1) * 64 + lane];
            aE = __builtin_amdgcn_mfma_f32_16x16x32_bf16(f0, kreg[kk],     aE, 0, 0, 0);
            aO = __builtin_amdgcn_mfma_f32_16x16x32_bf16(f1, kreg[kk + 1], aO, 0, 0, 0);
        }
        f32x4 acc2 = zf;
        #pragma unroll
        for (int kh = 0; kh < 2; ++kh) {
            bf16x8 f = W2F[(tile * 2 + kh) * 64 + lane];
            acc2 = __builtin_amdgcn_mfma_f32_16x16x32_bf16(f, hreg[kh], acc2, 0, 0, 0);
        }
        int nb = tile * 16 + lg * 4;
        float4 b2v = *reinterpret_cast<const float4*>(b2 + nb);
        float4 pbv = *reinterpret_cast<const float4*>(pb + nb);
        f32x4 pz, zz;
        pz[0] = acc2[0] + b2v.x; pz[1] = acc2[1] + b2v.y;
        pz[2] = acc2[2] + b2v.z; pz[3] = acc2[3] + b2v.w;
        zz[0] = aE[0] + aO[0] + pbv.x; zz[1] = aE[1] + aO[1] + pbv.y;
        zz[2] = aE[2] + aO[2] + pbv.z; zz[3] = aE[3] + aO[3] + pbv.w;
        predz[it] = pz; z3v[it] = zz;
    }

    // ---- writeback pass 1: pred (row-contiguous streams) + err capture ----
    // stage: lane (lh,lg) wrote cols wave*128+it*16+lg*4 of row lh
    #pragma unroll
    for (int it = 0; it < NIT; ++it) {
        int cb = (wave * 512 + it * 64 + lg * 16) ^ ((lh & 15) << 4);
        *reinterpret_cast<f32x4*>(xbuf + lh * 2048 + cb) = predz[it];
    }
    __syncthreads();
    float4 errs[NIT];
    float  fp[NIT];
    #pragma unroll
    for (int p = 0; p < NIT; ++p) {
        int row = wave * 4 + (p >> 1);               // wave owns 4 complete rows
        int ob  = (p & 1) * 1024 + lane * 16;        // byte offset within the row
        int rb  = ob ^ ((row & 15) << 4);
        float4 pr = *reinterpret_cast<const float4*>(xbuf + row * 2048 + rb);
        long ga = (row0 + row) * (long)DV + (ob >> 2);
        float4 va = *reinterpret_cast<const float4*>(value + ga);
        float4 er;
        er.x = fminf(fmaxf(va.x - pr.x, -3.f), 3.f);
        er.y = fminf(fmaxf(va.y - pr.y, -3.f), 3.f);
        er.z = fminf(fmaxf(va.z - pr.z, -3.f), 3.f);
        er.w = fminf(fmaxf(va.w - pr.w, -3.f), 3.f);
        errs[p] = er;
        *reinterpret_cast<float4*>(outPred + ga) = pr;   // 1KB contiguous per instr
    }
    __syncthreads();

    // ---- writeback pass 2: prec + err (row-contiguous) + F partials ----
    #pragma unroll
    for (int it = 0; it < NIT; ++it) {
        int cb = (wave * 512 + it * 64 + lg * 16) ^ ((lh & 15) << 4);
        *reinterpret_cast<f32x4*>(xbuf + lh * 2048 + cb) = z3v[it];
    }
    __syncthreads();
    #pragma unroll
    for (int p = 0; p < NIT; ++p) {
        int row = wave * 4 + (p >> 1);
        int ob  = (p & 1) * 1024 + lane * 16;
        int rb  = ob ^ ((row & 15) << 4);
        float4 zz = *reinterpret_cast<const float4*>(xbuf + row * 2048 + rb);
        long ga = (row0 + row) * (long)DV + (ob >> 2);
        float za[4] = {zz.x, zz.y, zz.z, zz.w};
        float ea[4] = {errs[p].x, errs[p].y, errs[p].z, errs[p].w};
        float pc[4], f = 0.f;
        #pragma unroll
        for (int r = 0; r < 4; ++r) {
            float z = za[r];
            float prec = fmaxf(z, 0.f) + __logf(1.0f + __expf(-fabsf(z))) + 0.01f;
            pc[r] = prec;
            f += prec * ea[r] * ea[r] - __logf(prec);
        }
        fp[p] = f;
        float4 pc4 = {pc[0], pc[1], pc[2], pc[3]};
        *reinterpret_cast<float4*>(outPrec + ga) = pc4;
        *reinterpret_cast<float4*>(outErr  + ga) = errs[p];
    }

    // ---- F: per row, reduce across the full wave (row covered by 2 p-steps) ----
    #pragma unroll
    for (int rr = 0; rr < 4; ++rr) {
        float s = fp[2 * rr] + fp[2 * rr + 1];
        #pragma unroll
        for (int off = 1; off < 64; off <<= 1)
            s += __shfl_xor(s, off, 64);
        if (lane == 0) outF[row0 + wave * 4 + rr] = s * (1.0f / 512.0f);
    }
}

extern "C" void kernel_launch(void* const* d_in, const int* in_sizes, int n_in,
                              void* d_out, int out_size, void* d_ws, size_t ws_size,
                              hipStream_t stream) {
    const float* key   = (const float*)d_in[0];
    const float* value = (const float*)d_in[1];
    const float* W1    = (const float*)d_in[2];
    const float* b1    = (const float*)d_in[3];
    const float* W2    = (const float*)d_in[4];
    const float* b2    = (const float*)d_in[5];
    const float* Wp    = (const float*)d_in[6];
    const float* pb    = (const float*)d_in[7];

    float* outF    = (float*)d_out;
    float* outPred = outF + BATCH;
    float* outPrec = outPred + (long)BATCH * DV;
    float* outErr  = outPrec + (long)BATCH * DV;

    conv_weights<<<160, 256, 0, stream>>>(W1, W2, Wp);
    fused_free_energy<<<BATCH / BMR, 256, 0, stream>>>(key, value, b1, b2, pb,
                                                       outF, outPred, outPrec, outErr);
}

// Round 12
// 272.134 us; speedup vs baseline: 1.5377x; 1.1025x over previous
//
#include <hip/hip_runtime.h>
#include <hip/hip_bf16.h>

#define BATCH 65536
#define DK 512
#define DV 512
#define DH 64
#define BMR 16          // rows per block

typedef __attribute__((ext_vector_type(8))) short bf16x8;
typedef __attribute__((ext_vector_type(4))) float f32x4;

// FRAGMENT-ORDERED bf16 weight images (one coalesced 1KB load per wave-frag):
//   shorts [0, 32768):       W1F  (4 tiles x 16 kk x 64 lanes x 8)
//   shorts [32768, 65536):   W2F  (32 tiles x 2 kh x 64 lanes x 8)
//   shorts [65536, 327680):  WpF  (32 tiles x 16 kk x 64 lanes x 8)
__device__ __align__(16) short g_wb[327680];

__device__ __forceinline__ short f2bf(float f) {
    union { __hip_bfloat16 h; short s; } u;
    u.h = __float2bfloat16(f);
    return u.s;
}

__device__ __forceinline__ bf16x8 pack8(float4 a, float4 b) {
    bf16x8 r;
    r[0] = f2bf(a.x); r[1] = f2bf(a.y); r[2] = f2bf(a.z); r[3] = f2bf(a.w);
    r[4] = f2bf(b.x); r[5] = f2bf(b.y); r[6] = f2bf(b.z); r[7] = f2bf(b.w);
    return r;
}

__global__ __launch_bounds__(256) void conv_weights(
    const float* __restrict__ W1, const float* __restrict__ W2,
    const float* __restrict__ Wp)
{
    int f = blockIdx.x * 256 + threadIdx.x;
    int lane = f & 63;
    const float* src; int stride, row, col;
    if (f < 4096) {                    // W1F
        int t = f >> 10, kk = (f >> 6) & 15;
        src = W1; stride = DK;
        row = t * 16 + (lane & 15); col = kk * 32 + (lane >> 4) * 8;
    } else if (f < 8192) {             // W2F
        int g = f - 4096; int t = g >> 7, kh = (g >> 6) & 1;
        src = W2; stride = DH;
        row = t * 16 + (lane & 15); col = kh * 32 + (lane >> 4) * 8;
    } else {                           // WpF
        int g = f - 8192; int t = g >> 10, kk = (g >> 6) & 15;
        src = Wp; stride = DK;
        row = t * 16 + (lane & 15); col = kk * 32 + (lane >> 4) * 8;
    }
    const float* p = src + (long)row * stride + col;
    float4 a = *reinterpret_cast<const float4*>(p);
    float4 b = *reinterpret_cast<const float4*>(p + 4);
    *reinterpret_cast<bf16x8*>(g_wb + (long)f * 8) = pack8(a, b);
}

// LDS layout (32 KB total):
//   [0, 16384):      key tile, bf16 [16 rows][512], byte ^= (row&7)<<4
//   [16384, 24576):  XP: pred stage f32 [16][128] (also hpark before main loop)
//   [24576, 32768):  XZ: z3 stage f32 [16][128]
#define KOF 0
#define XP  16384
#define XZ  24576

__global__ __launch_bounds__(256, 4) void fused_free_energy(
    const float* __restrict__ key, const float* __restrict__ value,
    const float* __restrict__ b1, const float* __restrict__ b2,
    const float* __restrict__ pb,
    float* __restrict__ outF, float* __restrict__ outPred,
    float* __restrict__ outPrec, float* __restrict__ outErr)
{
    __shared__ __align__(16) char lds[32768];

    const bf16x8* W1F = reinterpret_cast<const bf16x8*>(g_wb);
    const bf16x8* W2F = reinterpret_cast<const bf16x8*>(g_wb + 32768);
    const bf16x8* WpF = reinterpret_cast<const bf16x8*>(g_wb + 65536);

    const int tid  = threadIdx.x;
    const int wave = tid >> 6;
    const int lane = tid & 63;
    const int lh   = lane & 15;
    const int lg   = lane >> 4;
    const long row0 = (long)blockIdx.x * BMR;
    const f32x4 zf = {0.f, 0.f, 0.f, 0.f};

    // ---- stage key tile (16 x 512) f32 -> bf16, swizzled ----
    {
        #pragma unroll
        for (int i = 0; i < 4; ++i) {            // 1024 8-elem chunks / 256 thr
            int idx = i * 256 + tid;
            int r = idx >> 6, c8 = idx & 63;
            const float* p = key + (row0 + r) * DK + c8 * 8;
            float4 a = *reinterpret_cast<const float4*>(p);
            float4 b = *reinterpret_cast<const float4*>(p + 4);
            int byte = (r * 1024 + c8 * 16) ^ ((r & 7) << 4);
            *reinterpret_cast<bf16x8*>(lds + KOF + byte) = pack8(a, b);
        }
    }
    __syncthreads();

    // key B-fragment from LDS: row lh, k-offset kk*32 + lg*8 (bytes kk*64+lg*16)
    #define KFRAG(kk) (*reinterpret_cast<const bf16x8*>( \
        lds + KOF + ((lh * 1024 + (kk) * 64 + lg * 16) ^ ((lh & 7) << 4))))

    // ---- GEMM1: h = gelu(key @ W1^T + b1); redundant per wave (cheap) ----
    bf16x8 hreg[2];
    {
        short hs_all[16];
        #pragma unroll
        for (int jt = 0; jt < 4; ++jt) {
            f32x4 aE = zf, aO = zf;
            #pragma unroll
            for (int kk = 0; kk < 16; kk += 2) {
                bf16x8 f0 = W1F[(jt * 16 + kk) * 64 + lane];
                bf16x8 f1 = W1F[(jt * 16 + kk + 1) * 64 + lane];
                aE = __builtin_amdgcn_mfma_f32_16x16x32_bf16(f0, KFRAG(kk),     aE, 0, 0, 0);
                aO = __builtin_amdgcn_mfma_f32_16x16x32_bf16(f1, KFRAG(kk + 1), aO, 0, 0, 0);
            }
            float4 b1v = *reinterpret_cast<const float4*>(b1 + jt * 16 + lg * 4);
            float b1a[4] = {b1v.x, b1v.y, b1v.z, b1v.w};
            #pragma unroll
            for (int r = 0; r < 4; ++r) {
                float z = aE[r] + aO[r] + b1a[r];
                float g = 0.5f * z * (1.0f + erff(z * 0.70710678f));  // exact GELU
                hs_all[jt * 4 + r] = f2bf(g);
            }
        }
        // park h in XP (wave-private 2KB slots), reload in B-frag layout
        #pragma unroll
        for (int jt = 0; jt < 4; ++jt) {
            int hb = XP + wave * 2048 + ((lh * 128 + jt * 32 + lg * 8) ^ ((lh & 7) << 4));
            short4 hv = {hs_all[jt * 4 + 0], hs_all[jt * 4 + 1],
                         hs_all[jt * 4 + 2], hs_all[jt * 4 + 3]};
            *reinterpret_cast<short4*>(lds + hb) = hv;
        }
        __syncthreads();
        #pragma unroll
        for (int kh = 0; kh < 2; ++kh) {
            int byte = (lh * 128 + kh * 64 + lg * 16) ^ ((lh & 7) << 4);
            hreg[kh] = *reinterpret_cast<const bf16x8*>(lds + XP + wave * 2048 + byte);
        }
        __syncthreads();   // hpark dead; XP free for staging
    }

    // ---- main loop: 4 phases x 128 cols; compute -> LDS stage -> stream out ----
    float facc0 = 0.f, facc1 = 0.f;
    #pragma unroll 1
    for (int ot = 0; ot < 4; ++ot) {
        // compute 2 col-tiles for this wave, park pred/z3 in LDS stage
        #pragma unroll
        for (int sub = 0; sub < 2; ++sub) {
            const int tt = ot * 8 + wave * 2 + sub;   // global col-tile 0..31
            f32x4 aE = zf, aO = zf;
            #pragma unroll
            for (int kk = 0; kk < 16; kk += 2) {
                bf16x8 f0 = WpF[(tt * 16 + kk) * 64 + lane];
                bf16x8 f1 = WpF[(tt * 16 + kk + 1) * 64 + lane];
                aE = __builtin_amdgcn_mfma_f32_16x16x32_bf16(f0, KFRAG(kk),     aE, 0, 0, 0);
                aO = __builtin_amdgcn_mfma_f32_16x16x32_bf16(f1, KFRAG(kk + 1), aO, 0, 0, 0);
            }
            f32x4 acc2 = zf;
            #pragma unroll
            for (int kh = 0; kh < 2; ++kh) {
                bf16x8 f = W2F[(tt * 2 + kh) * 64 + lane];
                acc2 = __builtin_amdgcn_mfma_f32_16x16x32_bf16(f, hreg[kh], acc2, 0, 0, 0);
            }
            int nb = tt * 16 + lg * 4;
            float4 b2v = *reinterpret_cast<const float4*>(b2 + nb);
            float4 pbv = *reinterpret_cast<const float4*>(pb + nb);
            f32x4 pz, zz;
            pz[0] = acc2[0] + b2v.x; pz[1] = acc2[1] + b2v.y;
            pz[2] = acc2[2] + b2v.z; pz[3] = acc2[3] + b2v.w;
            zz[0] = aE[0] + aO[0] + pbv.x; zz[1] = aE[1] + aO[1] + pbv.y;
            zz[2] = aE[2] + aO[2] + pbv.z; zz[3] = aE[3] + aO[3] + pbv.w;
            int relb = (wave * 2 + sub) * 64 + lg * 16;            // byte 0..511
            int sb = (lh * 512 + relb) ^ ((lh & 7) << 4);
            *reinterpret_cast<f32x4*>(lds + XP + sb) = pz;
            *reinterpret_cast<f32x4*>(lds + XZ + sb) = zz;
        }
        __syncthreads();

        // writeback: wave streams 4 complete 128-col row segments (512B each)
        #pragma unroll
        for (int ch = 0; ch < 2; ++ch) {
            int row  = wave * 4 + (lane >> 5) + ch * 2;
            int colb = (lane & 31) * 16;                           // byte in segment
            int rb   = (row * 512 + colb) ^ ((row & 7) << 4);
            float4 pr = *reinterpret_cast<const float4*>(lds + XP + rb);
            float4 zz = *reinterpret_cast<const float4*>(lds + XZ + rb);
            long ga = (row0 + row) * (long)DV + ot * 128 + (lane & 31) * 4;
            float4 va = *reinterpret_cast<const float4*>(value + ga);
            float pa[4] = {pr.x, pr.y, pr.z, pr.w};
            float za[4] = {zz.x, zz.y, zz.z, zz.w};
            float vaa[4] = {va.x, va.y, va.z, va.w};
            float er[4], pc[4], f = 0.f;
            #pragma unroll
            for (int r = 0; r < 4; ++r) {
                float z = za[r];
                float prec = fmaxf(z, 0.f) + __logf(1.0f + __expf(-fabsf(z))) + 0.01f;
                float e = fminf(fmaxf(vaa[r] - pa[r], -3.f), 3.f);
                pc[r] = prec; er[r] = e;
                f += prec * e * e - __logf(prec);
            }
            float4 pc4 = {pc[0], pc[1], pc[2], pc[3]};
            float4 er4 = {er[0], er[1], er[2], er[3]};
            *reinterpret_cast<float4*>(outPred + ga) = pr;
            *reinterpret_cast<float4*>(outPrec + ga) = pc4;
            *reinterpret_cast<float4*>(outErr  + ga) = er4;
            if (ch == 0) facc0 += f; else facc1 += f;
        }
        __syncthreads();
    }

    // ---- F: reduce across the 32-lane group sharing a row ----
    #pragma unroll
    for (int ch = 0; ch < 2; ++ch) {
        float s = (ch == 0) ? facc0 : facc1;
        #pragma unroll
        for (int off = 1; off < 32; off <<= 1)
            s += __shfl_xor(s, off, 64);
        if ((lane & 31) == 0)
            outF[row0 + wave * 4 + (lane >> 5) + ch * 2] = s * (1.0f / 512.0f);
    }
}

extern "C" void kernel_launch(void* const* d_in, const int* in_sizes, int n_in,
                              void* d_out, int out_size, void* d_ws, size_t ws_size,
                              hipStream_t stream) {
    const float* key   = (const float*)d_in[0];
    const float* value = (const float*)d_in[1];
    const float* W1    = (const float*)d_in[2];
    const float* b1    = (const float*)d_in[3];
    const float* W2    = (const float*)d_in[4];
    const float* b2    = (const float*)d_in[5];
    const float* Wp    = (const float*)d_in[6];
    const float* pb    = (const float*)d_in[7];

    float* outF    = (float*)d_out;
    float* outPred = outF + BATCH;
    float* outPrec = outPred + (long)BATCH * DV;
    float* outErr  = outPrec + (long)BATCH * DV;

    conv_weights<<<160, 256, 0, stream>>>(W1, W2, Wp);
    fused_free_energy<<<BATCH / BMR, 256, 0, stream>>>(key, value, b1, b2, pb,
                                                       outF, outPred, outPrec, outErr);
}

// Round 13
// 261.263 us; speedup vs baseline: 1.6017x; 1.0416x over previous
//
#include <hip/hip_runtime.h>
#include <hip/hip_bf16.h>

#define BATCH 65536
#define DK 512
#define DV 512
#define DH 64
#define BMR 16          // rows per block

typedef __attribute__((ext_vector_type(8))) short bf16x8;
typedef __attribute__((ext_vector_type(4))) float f32x4;

// raw barrier pair: drain LDS ops (write->read visibility), do NOT drain vmcnt
#define LGKM_BAR() do { asm volatile("s_waitcnt lgkmcnt(0)" ::: "memory"); \
                        __builtin_amdgcn_s_barrier(); } while (0)
#define BAR()      do { asm volatile("" ::: "memory"); \
                        __builtin_amdgcn_s_barrier(); } while (0)

// FRAGMENT-ORDERED bf16 weight images (one coalesced 1KB load per wave-frag):
//   shorts [0, 32768):       W1F  (4 tiles x 16 kk x 64 lanes x 8)
//   shorts [32768, 65536):   W2F  (32 tiles x 2 kh x 64 lanes x 8)
//   shorts [65536, 327680):  WpF  (32 tiles x 16 kk x 64 lanes x 8)
__device__ __align__(16) short g_wb[327680];

__device__ __forceinline__ short f2bf(float f) {
    union { __hip_bfloat16 h; short s; } u;
    u.h = __float2bfloat16(f);
    return u.s;
}

__device__ __forceinline__ bf16x8 pack8(float4 a, float4 b) {
    bf16x8 r;
    r[0] = f2bf(a.x); r[1] = f2bf(a.y); r[2] = f2bf(a.z); r[3] = f2bf(a.w);
    r[4] = f2bf(b.x); r[5] = f2bf(b.y); r[6] = f2bf(b.z); r[7] = f2bf(b.w);
    return r;
}

__global__ __launch_bounds__(256) void conv_weights(
    const float* __restrict__ W1, const float* __restrict__ W2,
    const float* __restrict__ Wp)
{
    int f = blockIdx.x * 256 + threadIdx.x;
    int lane = f & 63;
    const float* src; int stride, row, col;
    if (f < 4096) {                    // W1F
        int t = f >> 10, kk = (f >> 6) & 15;
        src = W1; stride = DK;
        row = t * 16 + (lane & 15); col = kk * 32 + (lane >> 4) * 8;
    } else if (f < 8192) {             // W2F
        int g = f - 4096; int t = g >> 7, kh = (g >> 6) & 1;
        src = W2; stride = DH;
        row = t * 16 + (lane & 15); col = kh * 32 + (lane >> 4) * 8;
    } else {                           // WpF
        int g = f - 8192; int t = g >> 10, kk = (g >> 6) & 15;
        src = Wp; stride = DK;
        row = t * 16 + (lane & 15); col = kk * 32 + (lane >> 4) * 8;
    }
    const float* p = src + (long)row * stride + col;
    float4 a = *reinterpret_cast<const float4*>(p);
    float4 b = *reinterpret_cast<const float4*>(p + 4);
    *reinterpret_cast<bf16x8*>(g_wb + (long)f * 8) = pack8(a, b);
}

// LDS layout (32 KB total):
//   [0, 16384):      key tile, bf16 [16 rows][512], byte ^= (row&7)<<4
//   [16384, 24576):  XP: pred stage f32 [16][128] (also hpark before main loop)
//   [24576, 32768):  XZ: z3 stage f32 [16][128]
#define KOF 0
#define XP  16384
#define XZ  24576

__global__ __launch_bounds__(256, 4) void fused_free_energy(
    const float* __restrict__ key, const float* __restrict__ value,
    const float* __restrict__ b1, const float* __restrict__ b2,
    const float* __restrict__ pb,
    float* __restrict__ outF, float* __restrict__ outPred,
    float* __restrict__ outPrec, float* __restrict__ outErr)
{
    __shared__ __align__(16) char lds[32768];

    const bf16x8* W1F = reinterpret_cast<const bf16x8*>(g_wb);
    const bf16x8* W2F = reinterpret_cast<const bf16x8*>(g_wb + 32768);
    const bf16x8* WpF = reinterpret_cast<const bf16x8*>(g_wb + 65536);

    const int tid  = threadIdx.x;
    const int wave = tid >> 6;
    const int lane = tid & 63;
    const int lh   = lane & 15;
    const int lg   = lane >> 4;
    const long row0 = (long)blockIdx.x * BMR;
    const f32x4 zf = {0.f, 0.f, 0.f, 0.f};

    // writeback geometry (thread-constant)
    const int rowA  = wave * 4 + (lane >> 5);        // first of 2 rows (other +2)
    const int colw  = (lane & 31) * 4;               // f32 col within 128-col segment
    const float* vbase0 = value + (row0 + rowA) * (long)DV + colw;
    const float* vbase1 = vbase0 + 2 * DV;

    float4 vA0, vA1, vB0, vB1;                       // value prefetch double-buffer
#define PREF(p, d0, d1) do { \
        d0 = *reinterpret_cast<const float4*>(vbase0 + (p) * 128); \
        d1 = *reinterpret_cast<const float4*>(vbase1 + (p) * 128); } while (0)

    PREF(0, vA0, vA1);                               // phase-0 value in flight

    // ---- stage key tile (16 x 512) f32 -> bf16, swizzled ----
    {
        #pragma unroll
        for (int i = 0; i < 4; ++i) {            // 1024 8-elem chunks / 256 thr
            int idx = i * 256 + tid;
            int r = idx >> 6, c8 = idx & 63;
            const float* p = key + (row0 + r) * DK + c8 * 8;
            float4 a = *reinterpret_cast<const float4*>(p);
            float4 b = *reinterpret_cast<const float4*>(p + 4);
            int byte = (r * 1024 + c8 * 16) ^ ((r & 7) << 4);
            *reinterpret_cast<bf16x8*>(lds + KOF + byte) = pack8(a, b);
        }
    }
    LGKM_BAR();

    // key B-fragment from LDS: row lh, k-offset kk*32 + lg*8 (bytes kk*64+lg*16)
    #define KFRAG(kk) (*reinterpret_cast<const bf16x8*>( \
        lds + KOF + ((lh * 1024 + (kk) * 64 + lg * 16) ^ ((lh & 7) << 4))))

    // ---- GEMM1: h = gelu(key @ W1^T + b1); redundant per wave (cheap) ----
    bf16x8 hreg[2];
    {
        short hs_all[16];
        #pragma unroll
        for (int jt = 0; jt < 4; ++jt) {
            f32x4 aE = zf, aO = zf;
            #pragma unroll
            for (int kk = 0; kk < 16; kk += 2) {
                bf16x8 f0 = W1F[(jt * 16 + kk) * 64 + lane];
                bf16x8 f1 = W1F[(jt * 16 + kk + 1) * 64 + lane];
                aE = __builtin_amdgcn_mfma_f32_16x16x32_bf16(f0, KFRAG(kk),     aE, 0, 0, 0);
                aO = __builtin_amdgcn_mfma_f32_16x16x32_bf16(f1, KFRAG(kk + 1), aO, 0, 0, 0);
            }
            float4 b1v = *reinterpret_cast<const float4*>(b1 + jt * 16 + lg * 4);
            float b1a[4] = {b1v.x, b1v.y, b1v.z, b1v.w};
            #pragma unroll
            for (int r = 0; r < 4; ++r) {
                float z = aE[r] + aO[r] + b1a[r];
                float g = 0.5f * z * (1.0f + erff(z * 0.70710678f));  // exact GELU
                hs_all[jt * 4 + r] = f2bf(g);
            }
        }
        // park h in XP (wave-private 2KB slots), reload in B-frag layout
        #pragma unroll
        for (int jt = 0; jt < 4; ++jt) {
            int hb = XP + wave * 2048 + ((lh * 128 + jt * 32 + lg * 8) ^ ((lh & 7) << 4));
            short4 hv = {hs_all[jt * 4 + 0], hs_all[jt * 4 + 1],
                         hs_all[jt * 4 + 2], hs_all[jt * 4 + 3]};
            *reinterpret_cast<short4*>(lds + hb) = hv;
        }
        LGKM_BAR();
        #pragma unroll
        for (int kh = 0; kh < 2; ++kh) {
            int byte = (lh * 128 + kh * 64 + lg * 16) ^ ((lh & 7) << 4);
            hreg[kh] = *reinterpret_cast<const bf16x8*>(lds + XP + wave * 2048 + byte);
        }
        LGKM_BAR();   // own reads drained; XP free for staging
    }

    float facc0 = 0.f, facc1 = 0.f;

    // ---- one phase: compute 2 col-tiles -> LDS stage -> stream 128-col rows ----
#define COMPUTE(ot) do {                                                          \
        _Pragma("unroll")                                                         \
        for (int sub = 0; sub < 2; ++sub) {                                       \
            const int tt = (ot) * 8 + wave * 2 + sub;                             \
            f32x4 aE = zf, aO = zf;                                               \
            _Pragma("unroll")                                                     \
            for (int kk = 0; kk < 16; kk += 2) {                                  \
                bf16x8 f0 = WpF[(tt * 16 + kk) * 64 + lane];                      \
                bf16x8 f1 = WpF[(tt * 16 + kk + 1) * 64 + lane];                  \
                aE = __builtin_amdgcn_mfma_f32_16x16x32_bf16(f0, KFRAG(kk),     aE, 0, 0, 0); \
                aO = __builtin_amdgcn_mfma_f32_16x16x32_bf16(f1, KFRAG(kk + 1), aO, 0, 0, 0); \
            }                                                                     \
            f32x4 acc2 = zf;                                                      \
            _Pragma("unroll")                                                     \
            for (int kh = 0; kh < 2; ++kh) {                                      \
                bf16x8 f = W2F[(tt * 2 + kh) * 64 + lane];                        \
                acc2 = __builtin_amdgcn_mfma_f32_16x16x32_bf16(f, hreg[kh], acc2, 0, 0, 0); \
            }                                                                     \
            int nb = tt * 16 + lg * 4;                                            \
            float4 b2v = *reinterpret_cast<const float4*>(b2 + nb);               \
            float4 pbv = *reinterpret_cast<const float4*>(pb + nb);               \
            f32x4 pz, zz;                                                         \
            pz[0] = acc2[0] + b2v.x; pz[1] = acc2[1] + b2v.y;                     \
            pz[2] = acc2[2] + b2v.z; pz[3] = acc2[3] + b2v.w;                     \
            zz[0] = aE[0] + aO[0] + pbv.x; zz[1] = aE[1] + aO[1] + pbv.y;         \
            zz[2] = aE[2] + aO[2] + pbv.z; zz[3] = aE[3] + aO[3] + pbv.w;         \
            int relb = (wave * 2 + sub) * 64 + lg * 16;                           \
            int sb = (lh * 512 + relb) ^ ((lh & 7) << 4);                         \
            *reinterpret_cast<f32x4*>(lds + XP + sb) = pz;                        \
            *reinterpret_cast<f32x4*>(lds + XZ + sb) = zz;                        \
        }                                                                         \
    } while (0)

#define WRITEBACK(ot, v0, v1) do {                                                \
        _Pragma("unroll")                                                         \
        for (int ch = 0; ch < 2; ++ch) {                                          \
            int row  = rowA + ch * 2;                                             \
            int colb = (lane & 31) * 16;                                          \
            int rb   = (row * 512 + colb) ^ ((row & 7) << 4);                     \
            float4 pr = *reinterpret_cast<const float4*>(lds + XP + rb);          \
            float4 zv = *reinterpret_cast<const float4*>(lds + XZ + rb);          \
            long ga = (row0 + row) * (long)DV + (ot) * 128 + colw;                \
            float4 va = (ch == 0) ? (v0) : (v1);                                  \
            float pa[4]  = {pr.x, pr.y, pr.z, pr.w};                              \
            float za[4]  = {zv.x, zv.y, zv.z, zv.w};                              \
            float vaa[4] = {va.x, va.y, va.z, va.w};                              \
            float er[4], pc[4], f = 0.f;                                          \
            _Pragma("unroll")                                                     \
            for (int r = 0; r < 4; ++r) {                                         \
                float z = za[r];                                                  \
                float prec = fmaxf(z, 0.f) + __logf(1.0f + __expf(-fabsf(z))) + 0.01f; \
                float e = fminf(fmaxf(vaa[r] - pa[r], -3.f), 3.f);                \
                pc[r] = prec; er[r] = e;                                          \
                f += prec * e * e - __logf(prec);                                 \
            }                                                                     \
            float4 pc4 = {pc[0], pc[1], pc[2], pc[3]};                            \
            float4 er4 = {er[0], er[1], er[2], er[3]};                            \
            *reinterpret_cast<float4*>(outPred + ga) = pr;                        \
            *reinterpret_cast<float4*>(outPrec + ga) = pc4;                       \
            *reinterpret_cast<float4*>(outErr  + ga) = er4;                       \
            if (ch == 0) facc0 += f; else facc1 += f;                             \
        }                                                                         \
    } while (0)

    // ---- 4 phases, fully unrolled; value double-buffer alternates A/B ----
    COMPUTE(0); PREF(1, vB0, vB1); LGKM_BAR();
    WRITEBACK(0, vA0, vA1); BAR();

    COMPUTE(1); PREF(2, vA0, vA1); LGKM_BAR();
    WRITEBACK(1, vB0, vB1); BAR();

    COMPUTE(2); PREF(3, vB0, vB1); LGKM_BAR();
    WRITEBACK(2, vA0, vA1); BAR();

    COMPUTE(3); LGKM_BAR();
    WRITEBACK(3, vB0, vB1);

    // ---- F: reduce across the 32-lane group sharing a row ----
    #pragma unroll
    for (int ch = 0; ch < 2; ++ch) {
        float s = (ch == 0) ? facc0 : facc1;
        #pragma unroll
        for (int off = 1; off < 32; off <<= 1)
            s += __shfl_xor(s, off, 64);
        if ((lane & 31) == 0)
            outF[row0 + rowA + ch * 2] = s * (1.0f / 512.0f);
    }
}

extern "C" void kernel_launch(void* const* d_in, const int* in_sizes, int n_in,
                              void* d_out, int out_size, void* d_ws, size_t ws_size,
                              hipStream_t stream) {
    const float* key   = (const float*)d_in[0];
    const float* value = (const float*)d_in[1];
    const float* W1    = (const float*)d_in[2];
    const float* b1    = (const float*)d_in[3];
    const float* W2    = (const float*)d_in[4];
    const float* b2    = (const float*)d_in[5];
    const float* Wp    = (const float*)d_in[6];
    const float* pb    = (const float*)d_in[7];

    float* outF    = (float*)d_out;
    float* outPred = outF + BATCH;
    float* outPrec = outPred + (long)BATCH * DV;
    float* outErr  = outPrec + (long)BATCH * DV;

    conv_weights<<<160, 256, 0, stream>>>(W1, W2, Wp);
    fused_free_energy<<<BATCH / BMR, 256, 0, stream>>>(key, value, b1, b2, pb,
                                                       outF, outPred, outPrec, outErr);
}